// Round 15
// baseline (182.792 us; speedup 1.0000x reference)
//
#include <hip/hip_runtime.h>
#include <cstdint>
#include <cstddef>

#define NB 8
#define NTOK 2048
#define TOKENS (NB * NTOK)   // 16384
#define D 1024
#define E 64
#define CAP 40
#define EC (E * CAP)         // 2560
#define OUT_TENSOR ((size_t)TOKENS * EC)  // 41943040
#define CHUNKS 32
#define CHTOK 64

#define TOTAL_F4 20971520ull // (2*OUT_TENSOR)/4
#define S2 14745600ull       // K1 fill [0,S2) = 225 MB (R13-validated split)
                             // K2 fill [S2,TOTAL) = 95 MB
#define MAGIC 0x5A17ED42

typedef __attribute__((ext_vector_type(8))) short short8v;
typedef __attribute__((ext_vector_type(4))) float f32x4;

__device__ __forceinline__ unsigned short f2bf(float f) {
  unsigned u = __float_as_uint(f);
  unsigned r = (u + 0x7FFFu + ((u >> 16) & 1u)) >> 16;   // RNE
  return (unsigned short)r;
}

// Non-temporal zero store (evict-first, no L2 allocate). Validated +22 us (R11).
__device__ __forceinline__ void nt_zero(float4* p) {
  __builtin_nontemporal_store((f32x4){0.f, 0.f, 0.f, 0.f},
                              reinterpret_cast<f32x4*>(p));
}

// ============ Kernel 1: [gemm+gate || prep(+flags)+fill || fill] ============
// bid 0..255   : gemm+gate (verbatim R13). Issues A-prefetch, then each thread
//                acquire-spins on flags[tid] (set by prep role) before B loads.
// bid 256..511 : prep role — 1 wT element/thread + proxyacc zero (blocks
//                256/257), per-thread threadfence, then release-store
//                flags[bid-256]=MAGIC; then join fill.
// bid 256..1023: nt-fill out[0..S2) (same distribution as validated R13).
// Flag protocol is replay-safe: wT is a pure function of w, so a stale MAGIC
// from the previous replay short-circuits the wait while prep rewrites
// identical bytes (benign same-value race). First post-poison replay: flags
// are 0xAAAAAAAA != MAGIC -> gemm waits properly.
__global__ __launch_bounds__(256, 1) void k_gemmgate_prep_fill(
    const float* __restrict__ x, const float* __restrict__ w,
    const unsigned short* __restrict__ wTc,   // const view for gemm reads
    unsigned short* __restrict__ wT,
    const float* __restrict__ noise,
    int* __restrict__ i1o, int* __restrict__ i2o,
    float* __restrict__ g1o, float* __restrict__ g2o,
    float* __restrict__ proxyacc, float* __restrict__ zpart,
    int* __restrict__ flags, int* __restrict__ ctr2,
    float* __restrict__ out) {
  const int bid = blockIdx.x;
  const int tid = threadIdx.x;

  if (bid >= 256) {
    // ---------------- prep role (blocks 256..511) ----------------
    if (bid < 512) {
      int gid = (bid - 256) * 256 + tid;     // 0..65535
      int e = gid >> 10, k = gid & 1023;
      wT[gid] = f2bf(w[k * E + e]);
      if (bid == 256) proxyacc[tid] = 0.f;
      if (bid == 257) proxyacc[256 + tid] = 0.f;
      __threadfence();                        // make this thread's stores visible
      __syncthreads();                        // all threads fenced
      if (tid == 0)
        __hip_atomic_store(&flags[bid - 256], MAGIC, __ATOMIC_RELEASE,
                           __HIP_MEMORY_SCOPE_AGENT);
    }
    // ---------------- fill role (blocks 256..1023) ----------------
    float4* o4 = reinterpret_cast<float4*>(out);
    const size_t stride = 768 * 256;
    for (size_t q = (size_t)(bid - 256) * 256 + tid; q < S2; q += stride)
      nt_zero(&o4[q]);
    return;
  }

  // ---------------- gemm+gate role (blocks 0..255) ----------------
  if (bid == 0 && tid == 0) *ctr2 = 0;   // reset K2's completion counter (stream-ordered)

  const int m0 = bid * 64;
  const int l = tid & 63;
  const int wv = tid >> 6;
  const int h = l >> 4;
  const int r = l & 15;

  const float* xrow = x + (size_t)(m0 + 16 * wv + r) * D;

  f32x4 acc[4];
#pragma unroll
  for (int f = 0; f < 4; ++f) acc[f] = (f32x4){0.f, 0.f, 0.f, 0.f};

  f32x4 ua[2][2], va[2][2];
  short8v bb[2][2][4];

#define LOADA(BUF, C)                                                  \
  {                                                                    \
    _Pragma("unroll") for (int s = 0; s < 2; ++s) {                    \
      const int k0 = 64 * (C) + 32 * s + 8 * h;                        \
      ua[BUF][s] = *(const f32x4*)(xrow + k0);                         \
      va[BUF][s] = *(const f32x4*)(xrow + k0 + 4);                     \
    }                                                                  \
  }
#define LOADB(BUF, C)                                                  \
  {                                                                    \
    _Pragma("unroll") for (int s = 0; s < 2; ++s) {                    \
      const int k0 = 64 * (C) + 32 * s + 8 * h;                        \
      bb[BUF][s][0] = *(const short8v*)(wr0 + k0);                     \
      bb[BUF][s][1] = *(const short8v*)(wr1 + k0);                     \
      bb[BUF][s][2] = *(const short8v*)(wr2 + k0);                     \
      bb[BUF][s][3] = *(const short8v*)(wr3 + k0);                     \
    }                                                                  \
  }

  LOADA(0, 0);   // A prefetch hides under the prep wait

  // wait for prep: thread tid watches flags[tid] (1:1), then block barrier
  while (__hip_atomic_load(&flags[tid], __ATOMIC_ACQUIRE,
                           __HIP_MEMORY_SCOPE_AGENT) != MAGIC)
    __builtin_amdgcn_s_sleep(2);
  __syncthreads();

  const unsigned short* wr0 = wTc + (size_t)(r) * D;
  const unsigned short* wr1 = wTc + (size_t)(16 + r) * D;
  const unsigned short* wr2 = wTc + (size_t)(32 + r) * D;
  const unsigned short* wr3 = wTc + (size_t)(48 + r) * D;

  LOADB(0, 0);
#pragma unroll
  for (int c = 0; c < 16; ++c) {
    const int cur = c & 1;
    if (c < 15) { LOADA((c + 1) & 1, c + 1); LOADB((c + 1) & 1, c + 1); }
#pragma unroll
    for (int s = 0; s < 2; ++s) {
      f32x4 u = ua[cur][s];
      f32x4 v = va[cur][s];
      short8v av;
      av[0] = (short)f2bf(u.x); av[1] = (short)f2bf(u.y);
      av[2] = (short)f2bf(u.z); av[3] = (short)f2bf(u.w);
      av[4] = (short)f2bf(v.x); av[5] = (short)f2bf(v.y);
      av[6] = (short)f2bf(v.z); av[7] = (short)f2bf(v.w);
#pragma unroll
      for (int f = 0; f < 4; ++f)
        acc[f] = __builtin_amdgcn_mfma_f32_16x16x32_bf16(av, bb[cur][s][f], acc[f], 0, 0, 0);
    }
  }
#undef LOADA
#undef LOADB

  // ---- fused gate (verbatim validated R7/R13) ----
  const int bslot = (m0 >> 11) * E;
  float pxl0 = 0.f, pxl1 = 0.f, pxl2 = 0.f, pxl3 = 0.f;
  float zw = 0.f;
  int c1a[4], c2a[4];
  float g1a[4], g2a[4];
  bool routea[4];

#pragma unroll
  for (int rr = 0; rr < 4; ++rr) {
    float l0 = acc[0][rr], l1 = acc[1][rr], l2 = acc[2][rr], l3 = acc[3][rr];
    float m = fmaxf(fmaxf(l0, l1), fmaxf(l2, l3));
#pragma unroll
    for (int off = 1; off < 16; off <<= 1) m = fmaxf(m, __shfl_xor(m, off));
    float p0 = expf(l0 - m), p1 = expf(l1 - m), p2 = expf(l2 - m), p3 = expf(l3 - m);
    float s = p0 + p1 + p2 + p3;
#pragma unroll
    for (int off = 1; off < 16; off <<= 1) s += __shfl_xor(s, off);

    float m1 = fmaxf(fmaxf(p0, p1), fmaxf(p2, p3));
#pragma unroll
    for (int off = 1; off < 16; off <<= 1) m1 = fmaxf(m1, __shfl_xor(m1, off));
    int lidx = 999;
    if (p0 == m1) lidx = r;
    if (p1 == m1) lidx = min(lidx, 16 + r);
    if (p2 == m1) lidx = min(lidx, 32 + r);
    if (p3 == m1) lidx = min(lidx, 48 + r);
#pragma unroll
    for (int off = 1; off < 16; off <<= 1) lidx = min(lidx, __shfl_xor(lidx, off));
    int c1 = lidx;

    float q0 = (c1 == r) ? -1.f : p0;
    float q1 = (c1 == 16 + r) ? -1.f : p1;
    float q2 = (c1 == 32 + r) ? -1.f : p2;
    float q3 = (c1 == 48 + r) ? -1.f : p3;
    float m2 = fmaxf(fmaxf(q0, q1), fmaxf(q2, q3));
#pragma unroll
    for (int off = 1; off < 16; off <<= 1) m2 = fmaxf(m2, __shfl_xor(m2, off));
    int lidx2 = 999;
    if (q0 == m2) lidx2 = r;
    if (q1 == m2) lidx2 = min(lidx2, 16 + r);
    if (q2 == m2) lidx2 = min(lidx2, 32 + r);
    if (q3 == m2) lidx2 = min(lidx2, 48 + r);
#pragma unroll
    for (int off = 1; off < 16; off <<= 1) lidx2 = min(lidx2, __shfl_xor(lidx2, off));
    int c2 = lidx2;

    float g1 = m1 / s;
    float g2 = m2 / s;
    float denom = g1 + g2 + 1e-9f;
    float g1n = g1 / denom;
    float g2n = g2 / denom;
    int token = m0 + 16 * wv + 4 * h + rr;
    bool route = noise[token] < (g2n / 0.2f);

    c1a[rr] = c1; c2a[rr] = c2; g1a[rr] = g1n; g2a[rr] = g2n; routea[rr] = route;

    pxl0 += p0 / s; pxl1 += p1 / s; pxl2 += p2 / s; pxl3 += p3 / s;
    float lse = m + logf(s);
    zw += lse * lse;
  }

  if (r == 0) {
#pragma unroll
    for (int rr = 0; rr < 4; ++rr) {
      int token = m0 + 16 * wv + 4 * h + rr;
      i1o[token] = c1a[rr];
      i2o[token] = routea[rr] ? c2a[rr] : -1;
      g1o[token] = g1a[rr];
      g2o[token] = g2a[rr];
    }
  }

  pxl0 += __shfl_xor(pxl0, 16); pxl0 += __shfl_xor(pxl0, 32);
  pxl1 += __shfl_xor(pxl1, 16); pxl1 += __shfl_xor(pxl1, 32);
  pxl2 += __shfl_xor(pxl2, 16); pxl2 += __shfl_xor(pxl2, 32);
  pxl3 += __shfl_xor(pxl3, 16); pxl3 += __shfl_xor(pxl3, 32);
  if (l < 16) {
    atomicAdd(&proxyacc[bslot + r], pxl0);
    atomicAdd(&proxyacc[bslot + 16 + r], pxl1);
    atomicAdd(&proxyacc[bslot + 32 + r], pxl2);
    atomicAdd(&proxyacc[bslot + 48 + r], pxl3);
  }
  zw += __shfl_xor(zw, 16); zw += __shfl_xor(zw, 32);
  if (l == 0) zpart[bid * 4 + wv] = zw;
}

// ============ Kernel 2: [pos || fillB || scatter+final-after-spin] ============
// 584 blocks x 256 thr (all co-resident: no LDS except pos's 20.5 KB -> no
// deadlock). bid 0..7: pos (4 waves x 8 chunks); bid 8..519: nt-fill
// [S2,TOTAL); bid 520..583: spin until ctr2==520 (pos+fill all done, released
// with fences), then verbatim scatter + scalar losses.
__global__ __launch_bounds__(256) void k_pos_fill_scatter(
    const int* __restrict__ i1, const int* __restrict__ i2r,
    const float* __restrict__ g1, const float* __restrict__ g2,
    int4* __restrict__ tokinfo, int* __restrict__ count1,
    const float* __restrict__ zpart, const float* __restrict__ proxyacc,
    int* __restrict__ ctr2, float* __restrict__ out) {
  const int bid = blockIdx.x;
  const int tid = threadIdx.x;

  if (bid >= 8 && bid < 520) {
    // ---------------- fill role ----------------
    float4* o4 = reinterpret_cast<float4*>(out);
    const size_t stride = 512 * 256;
    for (size_t q = S2 + (size_t)(bid - 8) * 256 + tid; q < TOTAL_F4; q += stride)
      nt_zero(&o4[q]);
    __threadfence();
    __syncthreads();
    if (tid == 0) atomicAdd(ctr2, 1);
    return;
  }

  if (bid < 8) {
    // ---------------- pos role (4 waves x 8 chunks) ----------------
    __shared__ unsigned char pos1c[NTOK];
    __shared__ unsigned char pos2c[NTOK];
    __shared__ int cnt1[CHUNKS][E];
    __shared__ int cnt2[CHUNKS][E];

    const int b = bid;
    const int wave = tid >> 6;
    const int lane = tid & 63;
    const unsigned long long lt = (lane == 63) ? 0x7FFFFFFFFFFFFFFFull
                                               : ((1ull << lane) - 1ull);

#pragma unroll
    for (int ci = 0; ci < 8; ++ci) {
      const int c = wave * 8 + ci;
      const int base = c * CHTOK;
      int e1 = i1[b * NTOK + base + lane];
      int e2 = i2r[b * NTOK + base + lane];
      int p1 = 0, p2 = 0, myc1 = 0, myc2 = 0;
      for (int e = 0; e < E; ++e) {
        unsigned long long m1 = __ballot(e1 == e);
        unsigned long long m2 = __ballot(e2 == e);
        if (e1 == e) p1 = __popcll(m1 & lt);
        if (e2 == e) p2 = __popcll(m2 & lt);
        if (lane == e) { myc1 = __popcll(m1); myc2 = __popcll(m2); }
      }
      pos1c[base + lane] = (unsigned char)p1;
      pos2c[base + lane] = (unsigned char)p2;
      cnt1[c][lane] = myc1;
      cnt2[c][lane] = myc2;
    }
    __syncthreads();

    if (tid < E) {
      int run1 = 0, run2 = 0;
#pragma unroll 4
      for (int c = 0; c < CHUNKS; ++c) {
        int v1 = cnt1[c][tid]; cnt1[c][tid] = run1; run1 += v1;
        int v2 = cnt2[c][tid]; cnt2[c][tid] = run2; run2 += v2;
      }
      count1[b * E + tid] = run1;
    }
    __syncthreads();

#pragma unroll
    for (int ci = 0; ci < 8; ++ci) {
      const int c = wave * 8 + ci;
      const int base = c * CHTOK;
      const int t = b * NTOK + base + lane;
      int e1 = i1[t];
      int e2 = i2r[t];
      int pp1 = cnt1[c][e1] + (int)pos1c[base + lane];
      int w1 = (pp1 < CAP) ? e1 * CAP + pp1 : -1;
      int w2 = -1;
      if (e2 >= 0) {
        int pp2 = cnt2[c][e2] + (int)pos2c[base + lane];
        if (pp2 < CAP) w2 = e2 * CAP + pp2;
      }
      tokinfo[t] = make_int4(w1, w2, __float_as_int(g1[t]), __float_as_int(g2[t]));
    }
    __threadfence();
    __syncthreads();
    if (tid == 0) atomicAdd(ctr2, 1);
    return;
  }

  // ---------------- scatter+final role (bid 520..583) ----------------
  if (tid == 0) {
    while (__hip_atomic_load(ctr2, __ATOMIC_ACQUIRE,
                             __HIP_MEMORY_SCOPE_AGENT) != 520)
      __builtin_amdgcn_s_sleep(2);
  }
  __syncthreads();

  const int t = (bid - 520) * 256 + tid;
  {
    int4 ti = tokinfo[t];
    float* dispatch = out;
    float* combine = out + OUT_TENSOR;
    if (ti.x >= 0) {
      size_t off = (size_t)t * EC + ti.x;
      combine[off] = __int_as_float(ti.z);
      dispatch[off] = 1.f;
    }
    if (ti.y >= 0) {
      size_t off = (size_t)t * EC + ti.y;
      combine[off] = __int_as_float(ti.w);
      dispatch[off] = 1.f;
    }
  }

  if (bid == 520) {
    __shared__ float red[256];
    float zs = 0.f;
    for (int i = tid; i < 1024; i += 256) zs += zpart[i];
    red[tid] = zs;
    __syncthreads();
    for (int s = 128; s > 0; s >>= 1) {
      if (tid < s) red[tid] += red[tid + s];
      __syncthreads();
    }
    float ztot = red[0];
    __syncthreads();
    float bs = 0.f;
    for (int i = tid; i < 512; i += 256) bs += proxyacc[i] * (float)count1[i];
    red[tid] = bs;
    __syncthreads();
    for (int s = 128; s > 0; s >>= 1) {
      if (tid < s) red[tid] += red[tid + s];
      __syncthreads();
    }
    if (tid == 0) {
      out[2 * OUT_TENSOR] = red[0] / 524288.f;      // balance_loss
      out[2 * OUT_TENSOR + 1] = ztot / 16384.f;     // router_z_loss
    }
  }
}

extern "C" void kernel_launch(void* const* d_in, const int* in_sizes, int n_in,
                              void* d_out, int out_size, void* d_ws, size_t ws_size,
                              hipStream_t stream) {
  const float* x = (const float*)d_in[0];
  const float* w = (const float*)d_in[1];
  const float* noise = (const float*)d_in[2];
  float* out = (float*)d_out;

  float* ws = (float*)d_ws;
  int* i1 = (int*)ws;                          // 16384
  int* i2r = i1 + TOKENS;                      // 16384
  float* g1 = (float*)(i2r + TOKENS);          // 16384
  float* g2 = g1 + TOKENS;                     // 16384
  float* proxyacc = g2 + TOKENS;               // 512
  int* count1 = (int*)(proxyacc + 512);        // 512
  float* zpart = (float*)(count1 + 512);       // 1024
  unsigned short* wT = (unsigned short*)(zpart + 1024);   // 65536 ushorts (32768 f)
  int4* tokinfo = (int4*)((float*)wT + 32768);            // 16384 int4 (16B-aligned)
  int* flags = (int*)(tokinfo + TOKENS);       // 256
  int* ctr2 = flags + 256;                     // 1

  k_gemmgate_prep_fill<<<1024, 256, 0, stream>>>(x, w, wT, wT, noise, i1, i2r,
                                                 g1, g2, proxyacc, zpart,
                                                 flags, ctr2, out);
  k_pos_fill_scatter<<<584, 256, 0, stream>>>(i1, i2r, g1, g2, tokinfo, count1,
                                              zpart, proxyacc, ctr2, out);
}

// Round 16
// 113.026 us; speedup vs baseline: 1.6172x; 1.6172x over previous
//
#include <hip/hip_runtime.h>
#include <cstdint>
#include <cstddef>

#define NB 8
#define NTOK 2048
#define TOKENS (NB * NTOK)   // 16384
#define D 1024
#define E 64
#define CAP 40
#define EC (E * CAP)         // 2560
#define OUT_TENSOR ((size_t)TOKENS * EC)  // 41943040
#define CHUNKS 32            // per batch (k_pos)
#define CHTOK 64             // tokens per chunk (k_pos)

#define TOTAL_F4 20971520ull // (2*OUT_TENSOR)/4
#define S0 786432ull         // prep fill [0,S0) = 12 MB (256 blocks x 256 thr x 12)
#define S2 14745600ull       // K1 fill [S0,S2) = 213 MB = 768x256x71 iters exact
                             // K2 fill [S2,TOTAL) = 95 MB (R13-validated split)

typedef __attribute__((ext_vector_type(8))) short short8v;
typedef __attribute__((ext_vector_type(4))) float f32x4;

__device__ __forceinline__ unsigned short f2bf(float f) {
  unsigned u = __float_as_uint(f);
  unsigned r = (u + 0x7FFFu + ((u >> 16) & 1u)) >> 16;   // RNE
  return (unsigned short)r;
}

// Non-temporal zero store (evict-first, no L2 allocate). Validated +22 us (R11).
__device__ __forceinline__ void nt_zero(float4* p) {
  __builtin_nontemporal_store((f32x4){0.f, 0.f, 0.f, 0.f},
                              reinterpret_cast<f32x4*>(p));
}

// ---------------- Kernel 0: wT transpose + proxy zero + 12 MB fill ----------------
__global__ __launch_bounds__(256) void k_prep(const float* __restrict__ w,
                                              unsigned short* __restrict__ wT,
                                              float* __restrict__ proxyacc,
                                              float* __restrict__ out) {
  int gid = blockIdx.x * 256 + threadIdx.x;   // 65536 total
  int e = gid >> 10, k = gid & 1023;
  wT[gid] = f2bf(w[k * E + e]);
  if (blockIdx.x == 0) {
    proxyacc[threadIdx.x] = 0.f;
    proxyacc[threadIdx.x + 256] = 0.f;
  }
  // 12 MB of output fill rides along (prep is launch-latency-dominated)
  float4* o4 = reinterpret_cast<float4*>(out);
  size_t q = (size_t)blockIdx.x * 3072 + threadIdx.x;
#pragma unroll
  for (int i = 0; i < 12; ++i, q += 256) nt_zero(&o4[q]);
}

// ------- Kernel 1: [barrier-free gemm + in-register gate (fused) || nt fill] -------
// Blocks 0..255: verbatim validated R13 gemm+gate, except the x stream uses
// NON-TEMPORAL loads (read-once; stops x evicting the reused 128 KB wT in L2 —
// read-side analog of R11's +22 us NT-store fix).
// Blocks 256..1023: nt-fill out[S0..S2), 71 iters exact.
__global__ __launch_bounds__(256, 1) void k_gemmgate_fill(const float* __restrict__ x,
                                                          const unsigned short* __restrict__ wT,
                                                          const float* __restrict__ noise,
                                                          int* __restrict__ i1o, int* __restrict__ i2o,
                                                          float* __restrict__ g1o, float* __restrict__ g2o,
                                                          float* __restrict__ proxyacc,
                                                          float* __restrict__ zpart,
                                                          float* __restrict__ out) {
  const int tid = threadIdx.x;

  if (blockIdx.x >= 256) {
    float4* o4 = reinterpret_cast<float4*>(out);
    size_t q = S0 + (size_t)(blockIdx.x - 256) * 256 + tid;
#pragma unroll 4
    for (int i = 0; i < 71; ++i, q += 768 * 256) nt_zero(&o4[q]);
    return;
  }

  const int m0 = blockIdx.x * 64;
  const int l = tid & 63;
  const int wv = tid >> 6;
  const int h = l >> 4;        // k-subgroup 0..3
  const int r = l & 15;

  const float* xrow = x + (size_t)(m0 + 16 * wv + r) * D;
  const unsigned short* wr0 = wT + (size_t)(r) * D;
  const unsigned short* wr1 = wT + (size_t)(16 + r) * D;
  const unsigned short* wr2 = wT + (size_t)(32 + r) * D;
  const unsigned short* wr3 = wT + (size_t)(48 + r) * D;

  f32x4 acc[4];
#pragma unroll
  for (int f = 0; f < 4; ++f) acc[f] = (f32x4){0.f, 0.f, 0.f, 0.f};

  f32x4 ua[2][2], va[2][2];
  short8v bb[2][2][4];

#define LOAD(BUF, C)                                                   \
  {                                                                    \
    _Pragma("unroll") for (int s = 0; s < 2; ++s) {                    \
      const int k0 = 64 * (C) + 32 * s + 8 * h;                        \
      ua[BUF][s] = __builtin_nontemporal_load((const f32x4*)(xrow + k0));     \
      va[BUF][s] = __builtin_nontemporal_load((const f32x4*)(xrow + k0 + 4)); \
      bb[BUF][s][0] = *(const short8v*)(wr0 + k0);                     \
      bb[BUF][s][1] = *(const short8v*)(wr1 + k0);                     \
      bb[BUF][s][2] = *(const short8v*)(wr2 + k0);                     \
      bb[BUF][s][3] = *(const short8v*)(wr3 + k0);                     \
    }                                                                  \
  }

  LOAD(0, 0);
#pragma unroll
  for (int c = 0; c < 16; ++c) {
    const int cur = c & 1;              // compile-time under full unroll
    if (c < 15) LOAD((c + 1) & 1, c + 1);
#pragma unroll
    for (int s = 0; s < 2; ++s) {
      f32x4 u = ua[cur][s];
      f32x4 v = va[cur][s];
      short8v av;
      av[0] = (short)f2bf(u.x); av[1] = (short)f2bf(u.y);
      av[2] = (short)f2bf(u.z); av[3] = (short)f2bf(u.w);
      av[4] = (short)f2bf(v.x); av[5] = (short)f2bf(v.y);
      av[6] = (short)f2bf(v.z); av[7] = (short)f2bf(v.w);
#pragma unroll
      for (int f = 0; f < 4; ++f)
        acc[f] = __builtin_amdgcn_mfma_f32_16x16x32_bf16(av, bb[cur][s][f], acc[f], 0, 0, 0);
    }
  }
#undef LOAD

  // ---- fused gate (verbatim validated R7/R13): lane l=16h+r holds
  // acc[f][rr] = logits[token=m0+16wv+4h+rr][expert=16f+r] ----
  const int bslot = (m0 >> 11) * E;
  float pxl0 = 0.f, pxl1 = 0.f, pxl2 = 0.f, pxl3 = 0.f;
  float zw = 0.f;
  int c1a[4], c2a[4];
  float g1a[4], g2a[4];
  bool routea[4];

#pragma unroll
  for (int rr = 0; rr < 4; ++rr) {
    float l0 = acc[0][rr], l1 = acc[1][rr], l2 = acc[2][rr], l3 = acc[3][rr];
    float m = fmaxf(fmaxf(l0, l1), fmaxf(l2, l3));
#pragma unroll
    for (int off = 1; off < 16; off <<= 1) m = fmaxf(m, __shfl_xor(m, off));
    float p0 = expf(l0 - m), p1 = expf(l1 - m), p2 = expf(l2 - m), p3 = expf(l3 - m);
    float s = p0 + p1 + p2 + p3;
#pragma unroll
    for (int off = 1; off < 16; off <<= 1) s += __shfl_xor(s, off);

    float m1 = fmaxf(fmaxf(p0, p1), fmaxf(p2, p3));
#pragma unroll
    for (int off = 1; off < 16; off <<= 1) m1 = fmaxf(m1, __shfl_xor(m1, off));
    int lidx = 999;
    if (p0 == m1) lidx = r;
    if (p1 == m1) lidx = min(lidx, 16 + r);
    if (p2 == m1) lidx = min(lidx, 32 + r);
    if (p3 == m1) lidx = min(lidx, 48 + r);
#pragma unroll
    for (int off = 1; off < 16; off <<= 1) lidx = min(lidx, __shfl_xor(lidx, off));
    int c1 = lidx;

    float q0 = (c1 == r) ? -1.f : p0;
    float q1 = (c1 == 16 + r) ? -1.f : p1;
    float q2 = (c1 == 32 + r) ? -1.f : p2;
    float q3 = (c1 == 48 + r) ? -1.f : p3;
    float m2 = fmaxf(fmaxf(q0, q1), fmaxf(q2, q3));
#pragma unroll
    for (int off = 1; off < 16; off <<= 1) m2 = fmaxf(m2, __shfl_xor(m2, off));
    int lidx2 = 999;
    if (q0 == m2) lidx2 = r;
    if (q1 == m2) lidx2 = min(lidx2, 16 + r);
    if (q2 == m2) lidx2 = min(lidx2, 32 + r);
    if (q3 == m2) lidx2 = min(lidx2, 48 + r);
#pragma unroll
    for (int off = 1; off < 16; off <<= 1) lidx2 = min(lidx2, __shfl_xor(lidx2, off));
    int c2 = lidx2;

    float g1 = m1 / s;
    float g2 = m2 / s;
    float denom = g1 + g2 + 1e-9f;
    float g1n = g1 / denom;
    float g2n = g2 / denom;
    int token = m0 + 16 * wv + 4 * h + rr;
    bool route = noise[token] < (g2n / 0.2f);

    c1a[rr] = c1; c2a[rr] = c2; g1a[rr] = g1n; g2a[rr] = g2n; routea[rr] = route;

    pxl0 += p0 / s; pxl1 += p1 / s; pxl2 += p2 / s; pxl3 += p3 / s;
    float lse = m + logf(s);
    zw += lse * lse;
  }

  if (r == 0) {
#pragma unroll
    for (int rr = 0; rr < 4; ++rr) {
      int token = m0 + 16 * wv + 4 * h + rr;
      i1o[token] = c1a[rr];
      i2o[token] = routea[rr] ? c2a[rr] : -1;
      g1o[token] = g1a[rr];
      g2o[token] = g2a[rr];
    }
  }

  pxl0 += __shfl_xor(pxl0, 16); pxl0 += __shfl_xor(pxl0, 32);
  pxl1 += __shfl_xor(pxl1, 16); pxl1 += __shfl_xor(pxl1, 32);
  pxl2 += __shfl_xor(pxl2, 16); pxl2 += __shfl_xor(pxl2, 32);
  pxl3 += __shfl_xor(pxl3, 16); pxl3 += __shfl_xor(pxl3, 32);
  if (l < 16) {
    atomicAdd(&proxyacc[bslot + r], pxl0);
    atomicAdd(&proxyacc[bslot + 16 + r], pxl1);
    atomicAdd(&proxyacc[bslot + 32 + r], pxl2);
    atomicAdd(&proxyacc[bslot + 48 + r], pxl3);
  }
  zw += __shfl_xor(zw, 16); zw += __shfl_xor(zw, 32);
  if (l == 0) zpart[blockIdx.x * 4 + wv] = zw;
}

// ------------- Kernel 2: [pos blocks || nt fill blocks] (verbatim R13) -------------
__global__ __launch_bounds__(1024) void k_pos_fill(const int* __restrict__ i1,
                                                   const int* __restrict__ i2r,
                                                   const float* __restrict__ g1,
                                                   const float* __restrict__ g2,
                                                   int4* __restrict__ tokinfo,
                                                   int* __restrict__ count1,
                                                   float* __restrict__ out) {
  if (blockIdx.x >= NB) {
    const size_t fi = (size_t)blockIdx.x - NB;   // 0..511
    float4* o4 = reinterpret_cast<float4*>(out);
    for (size_t q = S2 + fi * 1024 + threadIdx.x; q < TOTAL_F4; q += (size_t)512 * 1024)
      nt_zero(&o4[q]);
    return;
  }
  __shared__ unsigned char pos1c[NTOK];
  __shared__ unsigned char pos2c[NTOK];
  __shared__ int cnt1[CHUNKS][E];
  __shared__ int cnt2[CHUNKS][E];

  const int b = blockIdx.x;
  const int tid = threadIdx.x;
  const int wave = tid >> 6;
  const int lane = tid & 63;
  const unsigned long long lt = (lane == 63) ? 0x7FFFFFFFFFFFFFFFull
                                             : ((1ull << lane) - 1ull);

#pragma unroll
  for (int ci = 0; ci < 2; ++ci) {
    const int c = wave * 2 + ci;
    const int base = c * CHTOK;
    int e1 = i1[b * NTOK + base + lane];
    int e2 = i2r[b * NTOK + base + lane];
    int p1 = 0, p2 = 0, myc1 = 0, myc2 = 0;
    for (int e = 0; e < E; ++e) {
      unsigned long long m1 = __ballot(e1 == e);
      unsigned long long m2 = __ballot(e2 == e);
      if (e1 == e) p1 = __popcll(m1 & lt);
      if (e2 == e) p2 = __popcll(m2 & lt);
      if (lane == e) { myc1 = __popcll(m1); myc2 = __popcll(m2); }
    }
    pos1c[base + lane] = (unsigned char)p1;
    pos2c[base + lane] = (unsigned char)p2;
    cnt1[c][lane] = myc1;
    cnt2[c][lane] = myc2;
  }
  __syncthreads();

  if (tid < E) {
    int run1 = 0, run2 = 0;
#pragma unroll 4
    for (int c = 0; c < CHUNKS; ++c) {
      int v1 = cnt1[c][tid]; cnt1[c][tid] = run1; run1 += v1;
      int v2 = cnt2[c][tid]; cnt2[c][tid] = run2; run2 += v2;
    }
    count1[b * E + tid] = run1;   // pre-capacity top-1 totals (density_1)
  }
  __syncthreads();

#pragma unroll
  for (int ci = 0; ci < 2; ++ci) {
    const int c = wave * 2 + ci;
    const int base = c * CHTOK;
    const int t = b * NTOK + base + lane;
    int e1 = i1[t];
    int e2 = i2r[t];
    int pp1 = cnt1[c][e1] + (int)pos1c[base + lane];
    int w1 = (pp1 < CAP) ? e1 * CAP + pp1 : -1;
    int w2 = -1;
    if (e2 >= 0) {
      int pp2 = cnt2[c][e2] + (int)pos2c[base + lane];
      if (pp2 < CAP) w2 = e2 * CAP + pp2;
    }
    tokinfo[t] = make_int4(w1, w2, __float_as_int(g1[t]), __float_as_int(g2[t]));
  }
}

// ------------- Kernel 3: sparse scatter + scalar losses (verbatim R13) -------------
__global__ __launch_bounds__(256) void k_scatter_final(const int4* __restrict__ tokinfo,
                                                       const float* __restrict__ zpart,
                                                       const float* __restrict__ proxyacc,
                                                       const int* __restrict__ count1,
                                                       float* __restrict__ out) {
  const int t = blockIdx.x * 256 + threadIdx.x;
  const int tid = threadIdx.x;
  if (t < TOKENS) {
    int4 ti = tokinfo[t];
    float* dispatch = out;
    float* combine = out + OUT_TENSOR;
    if (ti.x >= 0) {
      size_t off = (size_t)t * EC + ti.x;
      combine[off] = __int_as_float(ti.z);
      dispatch[off] = 1.f;
    }
    if (ti.y >= 0) {
      size_t off = (size_t)t * EC + ti.y;
      combine[off] = __int_as_float(ti.w);
      dispatch[off] = 1.f;
    }
  }

  if (blockIdx.x == 0) {
    __shared__ float red[256];
    float zs = 0.f;
    for (int i = tid; i < 1024; i += 256) zs += zpart[i];
    red[tid] = zs;
    __syncthreads();
    for (int s = 128; s > 0; s >>= 1) {
      if (tid < s) red[tid] += red[tid + s];
      __syncthreads();
    }
    float ztot = red[0];
    __syncthreads();
    float bs = 0.f;
    for (int i = tid; i < 512; i += 256) bs += proxyacc[i] * (float)count1[i];
    red[tid] = bs;
    __syncthreads();
    for (int s = 128; s > 0; s >>= 1) {
      if (tid < s) red[tid] += red[tid + s];
      __syncthreads();
    }
    if (tid == 0) {
      out[2 * OUT_TENSOR] = red[0] / 524288.f;      // balance_loss
      out[2 * OUT_TENSOR + 1] = ztot / 16384.f;     // router_z_loss
    }
  }
}

extern "C" void kernel_launch(void* const* d_in, const int* in_sizes, int n_in,
                              void* d_out, int out_size, void* d_ws, size_t ws_size,
                              hipStream_t stream) {
  const float* x = (const float*)d_in[0];
  const float* w = (const float*)d_in[1];
  const float* noise = (const float*)d_in[2];
  float* out = (float*)d_out;

  float* ws = (float*)d_ws;
  int* i1 = (int*)ws;                          // 16384
  int* i2r = i1 + TOKENS;                      // 16384
  float* g1 = (float*)(i2r + TOKENS);          // 16384
  float* g2 = g1 + TOKENS;                     // 16384
  float* proxyacc = g2 + TOKENS;               // 512
  int* count1 = (int*)(proxyacc + 512);        // 512
  float* zpart = (float*)(count1 + 512);       // 1024
  unsigned short* wT = (unsigned short*)(zpart + 1024);   // 65536 ushorts (32768 f)
  int4* tokinfo = (int4*)((float*)wT + 32768);            // 16384 int4 (16B-aligned)

  k_prep<<<256, 256, 0, stream>>>(w, wT, proxyacc, out);
  k_gemmgate_fill<<<1024, 256, 0, stream>>>(x, wT, noise, i1, i2r, g1, g2,
                                            proxyacc, zpart, out);
  k_pos_fill<<<NB + 512, 1024, 0, stream>>>(i1, i2r, g1, g2, tokinfo, count1, out);
  k_scatter_final<<<64, 256, 0, stream>>>(tokinfo, zpart, proxyacc, count1, out);
}

// Round 17
// 86.071 us; speedup vs baseline: 2.1237x; 1.3132x over previous
//
#include <hip/hip_runtime.h>
#include <cstdint>
#include <cstddef>

#define NB 8
#define NTOK 2048
#define TOKENS (NB * NTOK)   // 16384
#define D 1024
#define E 64
#define CAP 40
#define EC (E * CAP)         // 2560
#define OUT_TENSOR ((size_t)TOKENS * EC)  // 41943040
#define CHUNKS 32            // per batch (k_pos)
#define CHTOK 64             // tokens per chunk (k_pos)

#define TOTAL_F4 20971520ull // (2*OUT_TENSOR)/4
#define G0 12779520ull       // fill-block region [0,G0) = 195 MB = 768x256x65 exact
#define S2 14745600ull       // gemm-tail region [G0,S2) = 30 MB = 256x256x30 exact
                             // K2 fill [S2,TOTAL) = 95 MB (R13-validated split)

typedef __attribute__((ext_vector_type(8))) short short8v;
typedef __attribute__((ext_vector_type(4))) float f32x4;

__device__ __forceinline__ unsigned short f2bf(float f) {
  unsigned u = __float_as_uint(f);
  unsigned r = (u + 0x7FFFu + ((u >> 16) & 1u)) >> 16;   // RNE
  return (unsigned short)r;
}

// Non-temporal zero store (evict-first, no L2 allocate). Validated +22 us (R11).
// NOTE: NT *loads* were a -25 us regression (R16): same-line 16B loads refetch
// from HBM when the line isn't allocated in L2. NT only for write-once stores.
__device__ __forceinline__ void nt_zero(float4* p) {
  __builtin_nontemporal_store((f32x4){0.f, 0.f, 0.f, 0.f},
                              reinterpret_cast<f32x4*>(p));
}

// ---------------- Kernel 0: wT[e][k] = bf16(w[k][e]); zero proxyacc (R13-exact) ----------------
__global__ __launch_bounds__(256) void k_prep(const float* __restrict__ w,
                                              unsigned short* __restrict__ wT,
                                              float* __restrict__ proxyacc) {
  int gid = blockIdx.x * 256 + threadIdx.x;   // 65536 total
  int e = gid >> 10, k = gid & 1023;
  wT[gid] = f2bf(w[k * E + e]);
  if (blockIdx.x == 0) {
    proxyacc[threadIdx.x] = 0.f;
    proxyacc[threadIdx.x + 256] = 0.f;
  }
}

// ------- Kernel 1: [gemm + in-register gate + FILL TAIL || nt fill] -------
// Blocks 0..255: verbatim validated R13 gemm+gate (regular loads!), then each
// block fills its exclusive 30-f4/thread tail slice of [G0,S2) — reclaims the
// gemm-occupied CUs for fill BW once the ~20 us gemm chain retires.
// Blocks 256..1023: nt-fill out[0..G0), 65 iters exact.
__global__ __launch_bounds__(256, 1) void k_gemmgate_fill(const float* __restrict__ x,
                                                          const unsigned short* __restrict__ wT,
                                                          const float* __restrict__ noise,
                                                          int* __restrict__ i1o, int* __restrict__ i2o,
                                                          float* __restrict__ g1o, float* __restrict__ g2o,
                                                          float* __restrict__ proxyacc,
                                                          float* __restrict__ zpart,
                                                          float* __restrict__ out) {
  const int tid = threadIdx.x;

  if (blockIdx.x >= 256) {
    float4* o4 = reinterpret_cast<float4*>(out);
    size_t q = (size_t)(blockIdx.x - 256) * 256 + tid;
#pragma unroll 5
    for (int i = 0; i < 65; ++i, q += 768 * 256) nt_zero(&o4[q]);
    return;
  }

  const int m0 = blockIdx.x * 64;
  const int l = tid & 63;
  const int wv = tid >> 6;
  const int h = l >> 4;        // k-subgroup 0..3
  const int r = l & 15;

  const float* xrow = x + (size_t)(m0 + 16 * wv + r) * D;
  const unsigned short* wr0 = wT + (size_t)(r) * D;
  const unsigned short* wr1 = wT + (size_t)(16 + r) * D;
  const unsigned short* wr2 = wT + (size_t)(32 + r) * D;
  const unsigned short* wr3 = wT + (size_t)(48 + r) * D;

  f32x4 acc[4];
#pragma unroll
  for (int f = 0; f < 4; ++f) acc[f] = (f32x4){0.f, 0.f, 0.f, 0.f};

  f32x4 ua[2][2], va[2][2];
  short8v bb[2][2][4];

#define LOAD(BUF, C)                                                   \
  {                                                                    \
    _Pragma("unroll") for (int s = 0; s < 2; ++s) {                    \
      const int k0 = 64 * (C) + 32 * s + 8 * h;                        \
      ua[BUF][s] = *(const f32x4*)(xrow + k0);                         \
      va[BUF][s] = *(const f32x4*)(xrow + k0 + 4);                     \
      bb[BUF][s][0] = *(const short8v*)(wr0 + k0);                     \
      bb[BUF][s][1] = *(const short8v*)(wr1 + k0);                     \
      bb[BUF][s][2] = *(const short8v*)(wr2 + k0);                     \
      bb[BUF][s][3] = *(const short8v*)(wr3 + k0);                     \
    }                                                                  \
  }

  LOAD(0, 0);
#pragma unroll
  for (int c = 0; c < 16; ++c) {
    const int cur = c & 1;              // compile-time under full unroll
    if (c < 15) LOAD((c + 1) & 1, c + 1);
#pragma unroll
    for (int s = 0; s < 2; ++s) {
      f32x4 u = ua[cur][s];
      f32x4 v = va[cur][s];
      short8v av;
      av[0] = (short)f2bf(u.x); av[1] = (short)f2bf(u.y);
      av[2] = (short)f2bf(u.z); av[3] = (short)f2bf(u.w);
      av[4] = (short)f2bf(v.x); av[5] = (short)f2bf(v.y);
      av[6] = (short)f2bf(v.z); av[7] = (short)f2bf(v.w);
#pragma unroll
      for (int f = 0; f < 4; ++f)
        acc[f] = __builtin_amdgcn_mfma_f32_16x16x32_bf16(av, bb[cur][s][f], acc[f], 0, 0, 0);
    }
  }
#undef LOAD

  // ---- fused gate (verbatim validated R7/R13): lane l=16h+r holds
  // acc[f][rr] = logits[token=m0+16wv+4h+rr][expert=16f+r] ----
  const int bslot = (m0 >> 11) * E;
  float pxl0 = 0.f, pxl1 = 0.f, pxl2 = 0.f, pxl3 = 0.f;
  float zw = 0.f;
  int c1a[4], c2a[4];
  float g1a[4], g2a[4];
  bool routea[4];

#pragma unroll
  for (int rr = 0; rr < 4; ++rr) {
    float l0 = acc[0][rr], l1 = acc[1][rr], l2 = acc[2][rr], l3 = acc[3][rr];
    float m = fmaxf(fmaxf(l0, l1), fmaxf(l2, l3));
#pragma unroll
    for (int off = 1; off < 16; off <<= 1) m = fmaxf(m, __shfl_xor(m, off));
    float p0 = expf(l0 - m), p1 = expf(l1 - m), p2 = expf(l2 - m), p3 = expf(l3 - m);
    float s = p0 + p1 + p2 + p3;
#pragma unroll
    for (int off = 1; off < 16; off <<= 1) s += __shfl_xor(s, off);

    float m1 = fmaxf(fmaxf(p0, p1), fmaxf(p2, p3));
#pragma unroll
    for (int off = 1; off < 16; off <<= 1) m1 = fmaxf(m1, __shfl_xor(m1, off));
    int lidx = 999;
    if (p0 == m1) lidx = r;
    if (p1 == m1) lidx = min(lidx, 16 + r);
    if (p2 == m1) lidx = min(lidx, 32 + r);
    if (p3 == m1) lidx = min(lidx, 48 + r);
#pragma unroll
    for (int off = 1; off < 16; off <<= 1) lidx = min(lidx, __shfl_xor(lidx, off));
    int c1 = lidx;

    float q0 = (c1 == r) ? -1.f : p0;
    float q1 = (c1 == 16 + r) ? -1.f : p1;
    float q2 = (c1 == 32 + r) ? -1.f : p2;
    float q3 = (c1 == 48 + r) ? -1.f : p3;
    float m2 = fmaxf(fmaxf(q0, q1), fmaxf(q2, q3));
#pragma unroll
    for (int off = 1; off < 16; off <<= 1) m2 = fmaxf(m2, __shfl_xor(m2, off));
    int lidx2 = 999;
    if (q0 == m2) lidx2 = r;
    if (q1 == m2) lidx2 = min(lidx2, 16 + r);
    if (q2 == m2) lidx2 = min(lidx2, 32 + r);
    if (q3 == m2) lidx2 = min(lidx2, 48 + r);
#pragma unroll
    for (int off = 1; off < 16; off <<= 1) lidx2 = min(lidx2, __shfl_xor(lidx2, off));
    int c2 = lidx2;

    float g1 = m1 / s;
    float g2 = m2 / s;
    float denom = g1 + g2 + 1e-9f;
    float g1n = g1 / denom;
    float g2n = g2 / denom;
    int token = m0 + 16 * wv + 4 * h + rr;
    bool route = noise[token] < (g2n / 0.2f);

    c1a[rr] = c1; c2a[rr] = c2; g1a[rr] = g1n; g2a[rr] = g2n; routea[rr] = route;

    pxl0 += p0 / s; pxl1 += p1 / s; pxl2 += p2 / s; pxl3 += p3 / s;
    float lse = m + logf(s);
    zw += lse * lse;
  }

  if (r == 0) {
#pragma unroll
    for (int rr = 0; rr < 4; ++rr) {
      int token = m0 + 16 * wv + 4 * h + rr;
      i1o[token] = c1a[rr];
      i2o[token] = routea[rr] ? c2a[rr] : -1;
      g1o[token] = g1a[rr];
      g2o[token] = g2a[rr];
    }
  }

  pxl0 += __shfl_xor(pxl0, 16); pxl0 += __shfl_xor(pxl0, 32);
  pxl1 += __shfl_xor(pxl1, 16); pxl1 += __shfl_xor(pxl1, 32);
  pxl2 += __shfl_xor(pxl2, 16); pxl2 += __shfl_xor(pxl2, 32);
  pxl3 += __shfl_xor(pxl3, 16); pxl3 += __shfl_xor(pxl3, 32);
  if (l < 16) {
    atomicAdd(&proxyacc[bslot + r], pxl0);
    atomicAdd(&proxyacc[bslot + 16 + r], pxl1);
    atomicAdd(&proxyacc[bslot + 32 + r], pxl2);
    atomicAdd(&proxyacc[bslot + 48 + r], pxl3);
  }
  zw += __shfl_xor(zw, 16); zw += __shfl_xor(zw, 32);
  if (l == 0) zpart[blockIdx.x * 4 + wv] = zw;

  // ---- fill tail: this block's exclusive 30-f4/thread slice of [G0,S2) ----
  {
    float4* o4 = reinterpret_cast<float4*>(out);
    size_t q = G0 + (size_t)blockIdx.x * (256 * 30) + tid;
#pragma unroll 5
    for (int i = 0; i < 30; ++i, q += 256) nt_zero(&o4[q]);
  }
}

// ------------- Kernel 2: [pos blocks || nt fill blocks] (verbatim R13) -------------
__global__ __launch_bounds__(1024) void k_pos_fill(const int* __restrict__ i1,
                                                   const int* __restrict__ i2r,
                                                   const float* __restrict__ g1,
                                                   const float* __restrict__ g2,
                                                   int4* __restrict__ tokinfo,
                                                   int* __restrict__ count1,
                                                   float* __restrict__ out) {
  if (blockIdx.x >= NB) {
    const size_t fi = (size_t)blockIdx.x - NB;   // 0..511
    float4* o4 = reinterpret_cast<float4*>(out);
    for (size_t q = S2 + fi * 1024 + threadIdx.x; q < TOTAL_F4; q += (size_t)512 * 1024)
      nt_zero(&o4[q]);
    return;
  }
  __shared__ unsigned char pos1c[NTOK];
  __shared__ unsigned char pos2c[NTOK];
  __shared__ int cnt1[CHUNKS][E];
  __shared__ int cnt2[CHUNKS][E];

  const int b = blockIdx.x;
  const int tid = threadIdx.x;
  const int wave = tid >> 6;
  const int lane = tid & 63;
  const unsigned long long lt = (lane == 63) ? 0x7FFFFFFFFFFFFFFFull
                                             : ((1ull << lane) - 1ull);

#pragma unroll
  for (int ci = 0; ci < 2; ++ci) {
    const int c = wave * 2 + ci;
    const int base = c * CHTOK;
    int e1 = i1[b * NTOK + base + lane];
    int e2 = i2r[b * NTOK + base + lane];
    int p1 = 0, p2 = 0, myc1 = 0, myc2 = 0;
    for (int e = 0; e < E; ++e) {
      unsigned long long m1 = __ballot(e1 == e);
      unsigned long long m2 = __ballot(e2 == e);
      if (e1 == e) p1 = __popcll(m1 & lt);
      if (e2 == e) p2 = __popcll(m2 & lt);
      if (lane == e) { myc1 = __popcll(m1); myc2 = __popcll(m2); }
    }
    pos1c[base + lane] = (unsigned char)p1;
    pos2c[base + lane] = (unsigned char)p2;
    cnt1[c][lane] = myc1;
    cnt2[c][lane] = myc2;
  }
  __syncthreads();

  if (tid < E) {
    int run1 = 0, run2 = 0;
#pragma unroll 4
    for (int c = 0; c < CHUNKS; ++c) {
      int v1 = cnt1[c][tid]; cnt1[c][tid] = run1; run1 += v1;
      int v2 = cnt2[c][tid]; cnt2[c][tid] = run2; run2 += v2;
    }
    count1[b * E + tid] = run1;   // pre-capacity top-1 totals (density_1)
  }
  __syncthreads();

#pragma unroll
  for (int ci = 0; ci < 2; ++ci) {
    const int c = wave * 2 + ci;
    const int base = c * CHTOK;
    const int t = b * NTOK + base + lane;
    int e1 = i1[t];
    int e2 = i2r[t];
    int pp1 = cnt1[c][e1] + (int)pos1c[base + lane];
    int w1 = (pp1 < CAP) ? e1 * CAP + pp1 : -1;
    int w2 = -1;
    if (e2 >= 0) {
      int pp2 = cnt2[c][e2] + (int)pos2c[base + lane];
      if (pp2 < CAP) w2 = e2 * CAP + pp2;
    }
    tokinfo[t] = make_int4(w1, w2, __float_as_int(g1[t]), __float_as_int(g2[t]));
  }
}

// ------------- Kernel 3: sparse scatter + scalar losses (verbatim R13) -------------
__global__ __launch_bounds__(256) void k_scatter_final(const int4* __restrict__ tokinfo,
                                                       const float* __restrict__ zpart,
                                                       const float* __restrict__ proxyacc,
                                                       const int* __restrict__ count1,
                                                       float* __restrict__ out) {
  const int t = blockIdx.x * 256 + threadIdx.x;
  const int tid = threadIdx.x;
  if (t < TOKENS) {
    int4 ti = tokinfo[t];
    float* dispatch = out;
    float* combine = out + OUT_TENSOR;
    if (ti.x >= 0) {
      size_t off = (size_t)t * EC + ti.x;
      combine[off] = __int_as_float(ti.z);
      dispatch[off] = 1.f;
    }
    if (ti.y >= 0) {
      size_t off = (size_t)t * EC + ti.y;
      combine[off] = __int_as_float(ti.w);
      dispatch[off] = 1.f;
    }
  }

  if (blockIdx.x == 0) {
    __shared__ float red[256];
    float zs = 0.f;
    for (int i = tid; i < 1024; i += 256) zs += zpart[i];
    red[tid] = zs;
    __syncthreads();
    for (int s = 128; s > 0; s >>= 1) {
      if (tid < s) red[tid] += red[tid + s];
      __syncthreads();
    }
    float ztot = red[0];
    __syncthreads();
    float bs = 0.f;
    for (int i = tid; i < 512; i += 256) bs += proxyacc[i] * (float)count1[i];
    red[tid] = bs;
    __syncthreads();
    for (int s = 128; s > 0; s >>= 1) {
      if (tid < s) red[tid] += red[tid + s];
      __syncthreads();
    }
    if (tid == 0) {
      out[2 * OUT_TENSOR] = red[0] / 524288.f;      // balance_loss
      out[2 * OUT_TENSOR + 1] = ztot / 16384.f;     // router_z_loss
    }
  }
}

extern "C" void kernel_launch(void* const* d_in, const int* in_sizes, int n_in,
                              void* d_out, int out_size, void* d_ws, size_t ws_size,
                              hipStream_t stream) {
  const float* x = (const float*)d_in[0];
  const float* w = (const float*)d_in[1];
  const float* noise = (const float*)d_in[2];
  float* out = (float*)d_out;

  float* ws = (float*)d_ws;
  int* i1 = (int*)ws;                          // 16384
  int* i2r = i1 + TOKENS;                      // 16384
  float* g1 = (float*)(i2r + TOKENS);          // 16384
  float* g2 = g1 + TOKENS;                     // 16384
  float* proxyacc = g2 + TOKENS;               // 512
  int* count1 = (int*)(proxyacc + 512);        // 512
  float* zpart = (float*)(count1 + 512);       // 1024
  unsigned short* wT = (unsigned short*)(zpart + 1024);   // 65536 ushorts (32768 f)
  int4* tokinfo = (int4*)((float*)wT + 32768);            // 16384 int4 (16B-aligned)

  k_prep<<<256, 256, 0, stream>>>(w, wT, proxyacc);
  k_gemmgate_fill<<<1024, 256, 0, stream>>>(x, wT, noise, i1, i2r, g1, g2,
                                            proxyacc, zpart, out);
  k_pos_fill<<<NB + 512, 1024, 0, stream>>>(i1, i2r, g1, g2, tokinfo, count1, out);
  k_scatter_final<<<64, 256, 0, stream>>>(tokinfo, zpart, proxyacc, count1, out);
}